// Round 18
// baseline (25.517 us; speedup 1.0000x reference)
//
#include <hip/hip_runtime.h>

#define HH 64
#define WW 64
#define TT 16
#define NPIX (HH * WW * TT)   // 65536
#define HALO 10               // 4 + 2*3
#define HWH  (HALO * HALO)    // 100 halo (h,w) positions
#define CH_SZ (HWH * TT)      // 1600 floats per channel
#define NCH 15                // gui(9, prescaled) + est(3) + var(3, x gamma^2)

// lane i <- lane i-1 within 16-lane DPP rows (row_shr:1), 0-fill at row start.
__device__ __forceinline__ float dpp_up1(float x) {
    return __int_as_float(__builtin_amdgcn_update_dpp(
        0, __float_as_int(x), 0x111, 0xF, 0xF, true));
}
// lane i <- lane i+1 within 16-lane DPP rows (row_shl:1), 0-fill at row end.
__device__ __forceinline__ float dpp_dn1(float x) {
    return __int_as_float(__builtin_amdgcn_update_dpp(
        0, __float_as_int(x), 0x101, 0xF, 0xF, true));
}

// R17 champion structure (grid 256 x block 1024, 96KB f32 LDS, 1 block/CU,
// img global, K=2 + DPP, 16 waves = 2 pixel-groups x 8 column-splits;
// 25.3us, replay-stable) + constant-folding trims:
//  (1) guidance staged prescaled by sqrt(0.5*log2e*sigma) -> weight is
//      exp2f(-sb), no log2e mul (exp2f == v_exp_f32; neg is a free modifier)
//  (2) var staged x gamma^2 -> membership pass is d2 < vGc+vGn (no G2 mul)
//  (3) float4 staging: 400 lanes x 15 channels, 16B aligned both sides
// Membership = (d2==0) | (d2<V & vc!=0 & vn!=0): case-verified == reference.
__global__ __launch_bounds__(1024, 4) void statdenoise_kernel(
    const float* __restrict__ img,
    const float* __restrict__ gui,
    const float* __restrict__ est,
    const float* __restrict__ var,
    float* __restrict__ out)
{
    __shared__ float smem[NCH * CH_SZ];   // 96 KB; aliased by reduction later

    // sqrt(0.5*log2(e)*sigma): (a-b)^2 accumulates 0.72135*sig*d2 directly
    const float SQS2[9] = {0.26857913f, 0.26857913f, 0.26857913f,
                           6.00561198f, 6.00561198f, 6.00561198f,
                           2.68579130f, 2.68579130f, 2.68579130f};
    const float G2 = 8.45064899f;   // gamma^2 = 2.907^2

    const int tid  = threadIdx.x;
    const int lane = tid & 63;
    const int sw   = tid >> 6;      // wave 0..15
    const int s7   = sw & 7;        // column-split 0..7
    const int pg   = sw >> 3;       // pixel-group 0..1
    const int tg   = lane & 7;      // t-group 0..7
    const int hwl  = lane >> 3;     // 0..7
    const int t0   = tg * 2;        // owns t0, t0+1
    const int h0   = (blockIdx.x >> 4) << 2;   // tile origin
    const int w0   = (blockIdx.x & 15) << 2;

    // ---- stage 15 channels of the 10x10x16 halo as float4s (edge-clamped;
    //      OOB values masked later by inb, exactly as the clamped loads) ----
    if (tid < 400) {
        const int t   = (tid & 3) << 2;          // t-quad 0,4,8,12
        const int hwq = tid >> 2;                // 0..99
        const int hq  = (hwq * 205) >> 11;       // exact /10 for hwq<1024
        const int wq  = hwq - hq * 10;
        const int hs  = min(max(h0 - 3 + hq, 0), HH - 1);
        const int ws  = min(max(w0 - 3 + wq, 0), WW - 1);
        const int g   = (((hs << 6) + ws) << 4) + t;
        const int p   = hwq * 16 + t;
#pragma unroll
        for (int c = 0; c < 9; ++c) {
            float4 v = *(const float4*)&gui[c * NPIX + g];
            v.x *= SQS2[c]; v.y *= SQS2[c]; v.z *= SQS2[c]; v.w *= SQS2[c];
            *(float4*)&smem[c * CH_SZ + p] = v;
        }
#pragma unroll
        for (int c = 0; c < 3; ++c) {
            *(float4*)&smem[(9 + c) * CH_SZ + p] = *(const float4*)&est[c * NPIX + g];
            float4 v = *(const float4*)&var[c * NPIX + g];
            v.x *= G2; v.y *= G2; v.z *= G2; v.w *= G2;
            *(float4*)&smem[(12 + c) * CH_SZ + p] = v;
        }
    }
    __syncthreads();

    const int pidx = pg * 8 + hwl;        // tile pixel 0..15
    const int th = pidx >> 2, tw = pidx & 3;
    const int hg = h0 + th,  wg = w0 + tw;

    // center values from LDS (center is inside the halo)
    const int lc = (((th + 3) * 10) + (tw + 3)) * 16 + t0;
    float2 gc[9];
#pragma unroll
    for (int c = 0; c < 9; ++c) gc[c] = *(const float2*)&smem[c * CH_SZ + lc];
    float2 ec[3], vc[3];
#pragma unroll
    for (int c = 0; c < 3; ++c) {
        ec[c] = *(const float2*)&smem[(9 + c)  * CH_SZ + lc];
        vc[c] = *(const float2*)&smem[(12 + c) * CH_SZ + lc];   // already x G2
    }
    // column-invariant: center var nonzero (staged value==0 iff var==0)
    bool vcnz[3][2];
#pragma unroll
    for (int c = 0; c < 3; ++c) {
        vcnz[c][0] = (vc[c].x != 0.f);
        vcnz[c][1] = (vc[c].y != 0.f);
    }

    const bool vLo = (t0 != 0);    // dt=-1 valid; also masks DPP boundary garbage
    const bool vHi = (t0 != 14);   // dt=+1 valid; also masks DPP boundary garbage

    float acc[2][4] = {};   // per owned t: {r,g,b,wsum}

    int dh = s7 / 7 - 3, dw = s7 % 7 - 3;   // column r = s7, then += 8
    for (int r = s7; r < 49; r += 8) {
        // halo coords are ALWAYS in range: th+dh+3 in [0,9], tw+dw+3 in [0,9]
        const int lb  = ((th + dh + 3) * 10 + (tw + dw + 3)) * 16 + t0;
        const bool inb = ((unsigned)(hg + dh) < (unsigned)HH) &
                         ((unsigned)(wg + dw) < (unsigned)WW);
        // clamped global offset for img
        const int hhc = min(max(hg + dh, 0), HH - 1);
        const int wwc = min(max(wg + dw, 0), WW - 1);
        const int gnb = (((hhc << 6) + wwc) << 4) + t0;

        // ---- bilateral over 9 prescaled guidance channels, 6 pairs ----
        float sb[2][3] = {};
#pragma unroll
        for (int c = 0; c < 9; ++c) {
            float2 m = *(const float2*)&smem[c * CH_SZ + lb];
            float nv[4] = {dpp_up1(m.y), m.x, m.y, dpp_dn1(m.x)};   // t0-1..t0+2
#pragma unroll
            for (int e = 0; e < 2; ++e) {
                float ce = e ? gc[c].y : gc[c].x;
#pragma unroll
                for (int k = 0; k < 3; ++k) {
                    float d = ce - nv[e + k];
                    sb[e][k] = fmaf(d, d, sb[e][k]);   // all constants folded
                }
            }
        }

        // ---- membership (division-free Welch t-test, G2 folded into var) ----
        // mem = (d2==0) | (d2 < vGc+vGn & vc!=0 & vn!=0). Case-verified vs
        // reference (incl. v==0 kills and num==den==0 -> 0.5 -> member).
        // OOB h/w neighbors provably get weight 0 -> masked by inb.
        bool mem[2][3] = {{true, true, true}, {true, true, true}};
#pragma unroll
        for (int c = 0; c < 3; ++c) {
            float2 em = *(const float2*)&smem[(9 + c)  * CH_SZ + lb];
            float2 vm = *(const float2*)&smem[(12 + c) * CH_SZ + lb];
            float env[4] = {dpp_up1(em.y), em.x, em.y, dpp_dn1(em.x)};
            float vnv[4] = {dpp_up1(vm.y), vm.x, vm.y, dpp_dn1(vm.x)};
#pragma unroll
            for (int e = 0; e < 2; ++e) {
                float ece = e ? ec[c].y : ec[c].x;
                float vce = e ? vc[c].y : vc[c].x;
#pragma unroll
                for (int k = 0; k < 3; ++k) {
                    float d  = ece - env[e + k];
                    float d2 = d * d;
                    float V  = vce + vnv[e + k];           // G2*(vi+vj), pre-folded
                    bool ok = (d2 == 0.f) |
                              ((d2 < V) & vcnz[c][e] & (vnv[e + k] != 0.f));
                    mem[e][k] = mem[e][k] & ok;
                }
            }
        }

        // ---- weights ----
        float wt[2][3];
#pragma unroll
        for (int e = 0; e < 2; ++e) {
#pragma unroll
            for (int k = 0; k < 3; ++k) {
                bool ok = inb && mem[e][k];
                if (e == 0 && k == 0) ok = ok && vLo;   // tt = t0-1
                if (e == 1 && k == 2) ok = ok && vHi;   // tt = t0+2
                wt[e][k] = ok ? exp2f(-sb[e][k]) : 0.f; // v_exp_f32, neg free
            }
        }

        // ---- accumulate image (global path; consumed last, latency hidden) ----
#pragma unroll
        for (int c = 0; c < 3; ++c) {
            float2 im = *(const float2*)&img[c * NPIX + gnb];
            float iv[4] = {dpp_up1(im.y), im.x, im.y, dpp_dn1(im.x)};
#pragma unroll
            for (int e = 0; e < 2; ++e) {
                acc[e][c] = fmaf(wt[e][0], iv[e],
                            fmaf(wt[e][1], iv[e + 1],
                            fmaf(wt[e][2], iv[e + 2], acc[e][c])));
            }
        }
#pragma unroll
        for (int e = 0; e < 2; ++e)
            acc[e][3] += wt[e][0] + wt[e][1] + wt[e][2];

        dw += 8;
        while (dw > 3) { dw -= 7; ++dh; }
    }

    // ---- combine the 8 splits (alias staging LDS after all reads done) ----
    __syncthreads();
    float4* red = (float4*)smem;          // 2048 x float4 = 32 KB < 96 KB
    red[(sw * 64 + lane) * 2 + 0] = make_float4(acc[0][0], acc[0][1], acc[0][2], acc[0][3]);
    red[(sw * 64 + lane) * 2 + 1] = make_float4(acc[1][0], acc[1][1], acc[1][2], acc[1][3]);
    __syncthreads();

    if (tid < 256) {
        const int pg_ = tid >> 7, hwl_ = (tid >> 4) & 7, tg_ = (tid >> 1) & 7, e_ = tid & 1;
        float4 sum = make_float4(0.f, 0.f, 0.f, 0.f);
#pragma unroll
        for (int q = 0; q < 8; ++q) {
            const int swq = pg_ * 8 + q;
            float4 v = red[(swq * 64 + hwl_ * 8 + tg_) * 2 + e_];
            sum.x += v.x; sum.y += v.y; sum.z += v.z; sum.w += v.w;
        }
        const int pidx_ = pg_ * 8 + hwl_;
        const int th_ = pidx_ >> 2, tw_ = pidx_ & 3;
        const int px = ((((h0 + th_) << 6) + (w0 + tw_)) << 4) + tg_ * 2 + e_;
        const float inv = 1.f / sum.w;    // wsum >= 1 (center weight == 1)
        out[0 * NPIX + px] = sum.x * inv;
        out[1 * NPIX + px] = sum.y * inv;
        out[2 * NPIX + px] = sum.z * inv;
    }
}

extern "C" void kernel_launch(void* const* d_in, const int* in_sizes, int n_in,
                              void* d_out, int out_size, void* d_ws, size_t ws_size,
                              hipStream_t stream) {
    const float* img = (const float*)d_in[0];
    const float* gui = (const float*)d_in[1];
    const float* est = (const float*)d_in[2];
    const float* var = (const float*)d_in[3];
    float* out = (float*)d_out;

    dim3 grid(256);     // one 4x4x16 tile per block, 1 block per CU
    dim3 block(1024);   // 16 waves: 2 pixel-groups x 8 column-splits
    statdenoise_kernel<<<grid, block, 0, stream>>>(img, gui, est, var, out);
}